// Round 1
// baseline (3958.635 us; speedup 1.0000x reference)
//
#include <hip/hip_runtime.h>

#define TT 4096
#define OD 64
#define LOG2PI 1.8378770664093453

// ws layout (floats): [0..63] z (per-sensor time sums), [64..67] Sq (per-group sum of squares),
// [128 ..] ybar[TT][4] (group-mean coordinate u^T y, u = (1/4)*ones(16))

__global__ __launch_bounds__(64) void reduce_kernel(const float* __restrict__ track,
                                                    float* __restrict__ ws) {
    const int lane = threadIdx.x;            // 0..63, = sensor index j
    const int t0 = blockIdx.x * 16;
    float* zacc = ws;
    float* sqacc = ws + 64;
    float* ybar = ws + 128;
    const int g = ((lane >> 5) << 1) | (lane & 1);   // group = 2*state_comp + bias_class
    const bool writer = (lane == 0) || (lane == 1) || (lane == 32) || (lane == 33);
    float accz = 0.f, accsq = 0.f;
#pragma unroll 4
    for (int i = 0; i < 16; ++i) {
        const int t = t0 + i;
        const float v = track[t * OD + lane];
        accz += v;
        accsq += v * v;
        // sum over the 16 lanes sharing (bit5, bit0): xor over bits 1..4
        float s = v;
        s += __shfl_xor(s, 2, 64);
        s += __shfl_xor(s, 4, 64);
        s += __shfl_xor(s, 8, 64);
        s += __shfl_xor(s, 16, 64);
        if (writer) ybar[t * 4 + g] = 0.25f * s;   // u^T y, ||u||=1
    }
    atomicAdd(&zacc[lane], accz);
    float s2 = accsq;
    s2 += __shfl_xor(s2, 2, 64);
    s2 += __shfl_xor(s2, 4, 64);
    s2 += __shfl_xor(s2, 8, 64);
    s2 += __shfl_xor(s2, 16, 64);
    if (writer) atomicAdd(&sqacc[g], s2);
}

__global__ __launch_bounds__(64) void kf_kernel(const float* __restrict__ ws,
                                                const float* __restrict__ bias_scales,
                                                const float* __restrict__ obs_noise,
                                                const float* __restrict__ trans_noise,
                                                const float* __restrict__ transition_param,
                                                float* __restrict__ out) {
    __shared__ float sh[8];   // [0..3] sum_z per group, [4..7] sum_z2 per group
    const int lane = threadIdx.x;
    const float* z = ws;
    const float* Sq = ws + 64;
    const float* ybar = ws + 128;

    {
        const float zj = z[lane];
        float sz = zj, sz2 = zj * zj;
        sz += __shfl_xor(sz, 2, 64);   sz2 += __shfl_xor(sz2, 2, 64);
        sz += __shfl_xor(sz, 4, 64);   sz2 += __shfl_xor(sz2, 4, 64);
        sz += __shfl_xor(sz, 8, 64);   sz2 += __shfl_xor(sz2, 8, 64);
        sz += __shfl_xor(sz, 16, 64);  sz2 += __shfl_xor(sz2, 16, 64);
        const int g = ((lane >> 5) << 1) | (lane & 1);
        if (lane == 0 || lane == 1 || lane == 32 || lane == 33) {
            sh[g] = sz;
            sh[4 + g] = sz2;
        }
    }
    __syncthreads();
    if (lane != 0) return;

    const float a0 = transition_param[0];
    const float a1 = transition_param[1];
    const float q  = trans_noise[0] * trans_noise[0];
    const float rr = obs_noise[0] * obs_noise[0];
    const float b0 = bias_scales[0];
    const float b1 = bias_scales[1];

    // augmented state x = (s0, s1, b00, b01, b10, b11); obs g: y_g = 4*s_{g>>1} + x[2+g] + nu
    float P[6][6];
#pragma unroll
    for (int i = 0; i < 6; ++i)
#pragma unroll
        for (int j = 0; j < 6; ++j) P[i][j] = 0.f;
    P[0][0] = 1.f; P[1][1] = 1.f;
    P[2][2] = b0; P[3][3] = b1; P[4][4] = b0; P[5][5] = b1;
    float m[6] = {0.f, 0.f, 0.f, 0.f, 0.f, 0.f};
    double ll = 0.0;
    float sy2_0 = 0.f, sy2_1 = 0.f, sy2_2 = 0.f, sy2_3 = 0.f;

    const float4* yb4 = (const float4*)ybar;
    float4 y = yb4[0];
    for (int t = 0; t < TT; ++t) {
        float4 ynext = yb4[(t + 1 < TT) ? (t + 1) : t];   // prefetch

        // ---- predict: s0' = a0*s1 + w, s1' = a1*s0 + w ----
        {
            const float t0 = a0 * m[1], t1 = a1 * m[0];
            m[0] = t0; m[1] = t1;
        }
        {
            float n0[6], n1[6];
#pragma unroll
            for (int j = 2; j < 6; ++j) { n0[j] = a0 * P[1][j]; n1[j] = a1 * P[0][j]; }
            const float p00 = a0 * a0 * P[1][1] + q;
            const float p11 = a1 * a1 * P[0][0] + q;
            const float p01 = a0 * a1 * P[0][1];
            P[0][0] = p00; P[1][1] = p11; P[0][1] = p01; P[1][0] = p01;
#pragma unroll
            for (int j = 2; j < 6; ++j) {
                P[0][j] = n0[j]; P[j][0] = n0[j];
                P[1][j] = n1[j]; P[j][1] = n1[j];
            }
        }

        // ---- CP[g][j] = 4*P[g>>1][j] + P[2+g][j] ----
        float CP[4][6];
#pragma unroll
        for (int gg = 0; gg < 4; ++gg) {
            const int ii = gg >> 1;
#pragma unroll
            for (int j = 0; j < 6; ++j) CP[gg][j] = 4.f * P[ii][j] + P[2 + gg][j];
        }

        // ---- S (lower triangle), S[g][h] = 4*CP[g][h>>1] + CP[g][2+h] (+rr on diag) ----
        const float S00 = 4.f * CP[0][0] + CP[0][2] + rr;
        const float S10 = 4.f * CP[1][0] + CP[1][2];
        const float S11 = 4.f * CP[1][0] + CP[1][3] + rr;
        const float S20 = 4.f * CP[2][0] + CP[2][2];
        const float S21 = 4.f * CP[2][0] + CP[2][3];
        const float S22 = 4.f * CP[2][1] + CP[2][4] + rr;
        const float S30 = 4.f * CP[3][0] + CP[3][2];
        const float S31 = 4.f * CP[3][0] + CP[3][3];
        const float S32 = 4.f * CP[3][1] + CP[3][4];
        const float S33 = 4.f * CP[3][1] + CP[3][5] + rr;

        // ---- Cholesky 4x4 with inverse diagonals ----
        const float d0 = S00;                               const float i0 = rsqrtf(d0);
        const float L10 = S10 * i0;
        const float L20 = S20 * i0;
        const float L30 = S30 * i0;
        const float d1 = S11 - L10 * L10;                   const float i1 = rsqrtf(d1);
        const float L21 = (S21 - L20 * L10) * i1;
        const float L31 = (S31 - L30 * L10) * i1;
        const float d2 = S22 - L20 * L20 - L21 * L21;       const float i2 = rsqrtf(d2);
        const float L32 = (S32 - L30 * L20 - L31 * L21) * i2;
        const float d3 = S33 - L30 * L30 - L31 * L31 - L32 * L32;  const float i3 = rsqrtf(d3);

        // ---- innovation ----
        const float mu0 = 4.f * m[0] + m[2];
        const float mu1 = 4.f * m[0] + m[3];
        const float mu2 = 4.f * m[1] + m[4];
        const float mu3 = 4.f * m[1] + m[5];
        const float r0 = y.x - mu0, r1 = y.y - mu1, r2 = y.z - mu2, r3 = y.w - mu3;
        sy2_0 += y.x * y.x; sy2_1 += y.y * y.y; sy2_2 += y.z * y.z; sy2_3 += y.w * y.w;

        // forward solve w = L^-1 r;  quad = ||w||^2
        const float w0 = r0 * i0;
        const float w1 = (r1 - L10 * w0) * i1;
        const float w2 = (r2 - L20 * w0 - L21 * w1) * i2;
        const float w3 = (r3 - L30 * w0 - L31 * w1 - L32 * w2) * i3;
        const float quad = w0 * w0 + w1 * w1 + w2 * w2 + w3 * w3;
        // back solve alpha = L^-T w
        const float al3 = w3 * i3;
        const float al2 = (w2 - L32 * al3) * i2;
        const float al1 = (w1 - L21 * al2 - L31 * al3) * i1;
        const float al0 = (w0 - L10 * al1 - L20 * al2 - L30 * al3) * i0;

        // per-step: -0.5*quad - sum(log Lii);  sum(log Lii) = 0.5*log(d0*d1*d2*d3)
        ll += (double)(-0.5f * quad - 0.5f * logf(d0 * d1 * d2 * d3));

        // ---- mean update: m += CP^T alpha ----
#pragma unroll
        for (int j = 0; j < 6; ++j)
            m[j] += CP[0][j] * al0 + CP[1][j] * al1 + CP[2][j] * al2 + CP[3][j] * al3;

        // ---- cov update: P -= CP^T S^-1 CP (upper triangle + mirror) ----
#pragma unroll
        for (int k = 0; k < 6; ++k) {
            const float u0 = CP[0][k] * i0;
            const float u1 = (CP[1][k] - L10 * u0) * i1;
            const float u2 = (CP[2][k] - L20 * u0 - L21 * u1) * i2;
            const float u3 = (CP[3][k] - L30 * u0 - L31 * u1 - L32 * u2) * i3;
            const float v3 = u3 * i3;
            const float v2 = (u2 - L32 * v3) * i2;
            const float v1 = (u1 - L21 * v2 - L31 * v3) * i1;
            const float v0 = (u0 - L10 * v1 - L20 * v2 - L30 * v3) * i0;
#pragma unroll
            for (int j = 0; j <= k; ++j) {
                const float dlt = CP[0][j] * v0 + CP[1][j] * v1 + CP[2][j] * v2 + CP[3][j] * v3;
                const float nv = P[j][k] - dlt;
                P[j][k] = nv; P[k][j] = nv;
            }
        }

        y = ynext;
    }

    // KF per-step constants: -0.5 * 4 * LOG2PI each step
    double llc = ll - 2.0 * LOG2PI * (double)TT;

    // ---- contrast coordinates: 15 per group, w_t = beta + nu_t ----
    const float bgv[4] = {b0, b1, b0, b1};
    const float sy2v[4] = {sy2_0, sy2_1, sy2_2, sy2_3};
    const double T_ = (double)TT;
#pragma unroll
    for (int gg = 0; gg < 4; ++gg) {
        const double b = (double)bgv[gg];
        const double r = (double)rr;
        const double sumz = (double)sh[gg];
        const double sumz2 = (double)sh[4 + gg];
        const double Zp = sumz2 - sumz * sumz / 16.0;          // sum over contrasts of (sum_t w)^2
        const double Sqp = (double)Sq[gg] - (double)sy2v[gg];   // sum over contrasts,t of w^2
        llc += -0.5 * Sqp / r
               + 0.5 * (b / (r * (r + T_ * b))) * Zp
               - 7.5 * ((T_ - 1.0) * log(r) + log(r + T_ * b))
               - 7.5 * T_ * LOG2PI;
    }

    out[0] = (float)llc;
}

extern "C" void kernel_launch(void* const* d_in, const int* in_sizes, int n_in,
                              void* d_out, int out_size, void* d_ws, size_t ws_size,
                              hipStream_t stream) {
    const float* track            = (const float*)d_in[0];
    const float* bias_scales      = (const float*)d_in[1];
    const float* obs_noise        = (const float*)d_in[2];
    const float* trans_noise      = (const float*)d_in[3];
    const float* transition_param = (const float*)d_in[4];
    float* ws = (float*)d_ws;
    float* out = (float*)d_out;

    // zero the accumulator region (z[64] + Sq[4]); ws is poisoned 0xAA each call
    hipMemsetAsync(ws, 0, 512, stream);
    reduce_kernel<<<TT / 16, 64, 0, stream>>>(track, ws);
    kf_kernel<<<1, 64, 0, stream>>>(ws, bias_scales, obs_noise, trans_noise, transition_param, out);
}

// Round 2
// 118.872 us; speedup vs baseline: 33.3018x; 33.3018x over previous
//
#include <hip/hip_runtime.h>

#define TT 4096
#define OD 64

// ws layout (floats):
//   [0..63]    z   (per-sensor time sums)
//   [64..67]   Sq  (per-group sum of squares of raw obs)
//   [68..71]   sy2 (per-group sum over t of ybar^2)
//   [128..16511]  ybar[TT][4]  (group-mean coordinate u^T y, ||u||=1, u=0.25*ones)
//   [16640 ..]    element pool: 4095 elements x 16 floats (AoS, 64B each)

__global__ __launch_bounds__(64) void reduce_kernel(const float* __restrict__ track,
                                                    float* __restrict__ ws) {
    const int lane = threadIdx.x;            // 0..63 = sensor index j
    const int t0 = blockIdx.x * 16;
    float* zacc = ws;
    float* sqacc = ws + 64;
    float* sy2acc = ws + 68;
    float* ybar = ws + 128;
    const int g = ((lane >> 5) << 1) | (lane & 1);   // group = 2*state_comp + bias_class
    const bool writer = (lane == 0) || (lane == 1) || (lane == 32) || (lane == 33);
    float accz = 0.f, accsq = 0.f, accy2 = 0.f;
#pragma unroll 4
    for (int i = 0; i < 16; ++i) {
        const int t = t0 + i;
        const float v = track[t * OD + lane];
        accz += v;
        accsq += v * v;
        float s = v;
        s += __shfl_xor(s, 2, 64);
        s += __shfl_xor(s, 4, 64);
        s += __shfl_xor(s, 8, 64);
        s += __shfl_xor(s, 16, 64);
        if (writer) {
            const float yb = 0.25f * s;
            ybar[t * 4 + g] = yb;
            accy2 += yb * yb;
        }
    }
    atomicAdd(&zacc[lane], accz);
    float s2 = accsq;
    s2 += __shfl_xor(s2, 2, 64);
    s2 += __shfl_xor(s2, 4, 64);
    s2 += __shfl_xor(s2, 8, 64);
    s2 += __shfl_xor(s2, 16, 64);
    if (writer) {
        atomicAdd(&sqacc[g], s2);
        atomicAdd(&sy2acc[g], accy2);
    }
}

// Element: psi(u,v) = exp(g) N(v; A u + b, C) exp(eta^T u - 0.5 u^T J u)
// Structure preserved at every level: A rows 2..5 = e_{2..5}; C nonzero only top-left 2x2.
// Per-level shared (LDS, 81 floats): At[12](2x6) | Ct[4](2x2) | J[36] | Gt[12] | GAt[12] | GC2[4] | clev

__device__ __forceinline__ void leaf_build(const float4 y, const float* __restrict__ sl,
                                           float b[6], float h[6], float& g) {
    // sl: {c, 1/rr, kappa, 4*a0, 4*a1, glc}
    const float bs0 = y.x + y.y, bs1 = y.z + y.w;
    const float v0 = y.x * sl[1] - sl[0] * bs0;
    const float v1 = y.y * sl[1] - sl[0] * bs0;
    const float v2 = y.z * sl[1] - sl[0] * bs1;
    const float v3 = y.w * sl[1] - sl[0] * bs1;
    b[0] = sl[2] * bs0; b[1] = sl[2] * bs1; b[2] = 0.f; b[3] = 0.f; b[4] = 0.f; b[5] = 0.f;
    h[0] = sl[4] * (v2 + v3); h[1] = sl[3] * (v0 + v1);
    h[2] = v0; h[3] = v1; h[4] = v2; h[5] = v3;
    g = -0.5f * (y.x * v0 + y.y * v1 + y.z * v2 + y.w * v3) - sl[5];
}

__device__ __forceinline__ void compose_el(const float* __restrict__ L,
                                           const float b1[6], const float h1[6], float g1,
                                           const float b2[6], const float h2[6], float g2,
                                           float bo[6], float ho[6], float& go) {
    const float* At = L;        // 2x6
    const float* Ct = L + 12;   // 2x2
    const float* J = L + 16;    // 6x6
    const float* Gt = L + 52;   // 2x6 (rows 0,1 of G; rows 2..5 = e)
    const float* GAt = L + 64;  // 2x6 (rows 0,1 of G*A)
    const float* GC2 = L + 76;  // 2x2 (= top 2x2 of G*C)
    float Jb[6];
#pragma unroll
    for (int i = 0; i < 6; ++i)
        Jb[i] = J[i * 6 + 0] * b1[0] + J[i * 6 + 1] * b1[1] + J[i * 6 + 2] * b1[2]
              + J[i * 6 + 3] * b1[3] + J[i * 6 + 4] * b1[4] + J[i * 6 + 5] * b1[5];
    const float Gb0 = Gt[0] * b1[0] + Gt[1] * b1[1] + Gt[2] * b1[2] + Gt[3] * b1[3] + Gt[4] * b1[4] + Gt[5] * b1[5];
    const float Gb1 = Gt[6] * b1[0] + Gt[7] * b1[1] + Gt[8] * b1[2] + Gt[9] * b1[3] + Gt[10] * b1[4] + Gt[11] * b1[5];
    // t = b1 + C*eta2 (only top-2 differ from b1)
    const float t0 = b1[0] + Ct[0] * h2[0] + Ct[1] * h2[1];
    const float t1 = b1[1] + Ct[2] * h2[0] + Ct[3] * h2[1];
    // u = G t (rows 2..5: u = t = b1)
    const float u0 = Gt[0] * t0 + Gt[1] * t1 + Gt[2] * b1[2] + Gt[3] * b1[3] + Gt[4] * b1[4] + Gt[5] * b1[5];
    const float u1 = Gt[6] * t0 + Gt[7] * t1 + Gt[8] * b1[2] + Gt[9] * b1[3] + Gt[10] * b1[4] + Gt[11] * b1[5];
    bo[0] = At[0] * u0 + At[1] * u1 + At[2] * b1[2] + At[3] * b1[3] + At[4] * b1[4] + At[5] * b1[5] + b2[0];
    bo[1] = At[6] * u0 + At[7] * u1 + At[8] * b1[2] + At[9] * b1[3] + At[10] * b1[4] + At[11] * b1[5] + b2[1];
#pragma unroll
    for (int j = 2; j < 6; ++j) bo[j] = b1[j] + b2[j];
    float w[6];
#pragma unroll
    for (int j = 0; j < 6; ++j) w[j] = h2[j] - Jb[j];
    ho[0] = h1[0] + w[0] * GAt[0] + w[1] * GAt[6];
    ho[1] = h1[1] + w[0] * GAt[1] + w[1] * GAt[7];
#pragma unroll
    for (int j = 2; j < 6; ++j) ho[j] = h1[j] + w[0] * GAt[j] + w[1] * GAt[6 + j] + w[j];
    // g' = g1+g2+clev - 0.5 b1'(JG)b1 + eta2' G b1 + 0.5 eta2' (GC) eta2
    const float q1 = Jb[0] * Gb0 + Jb[1] * Gb1 + Jb[2] * b1[2] + Jb[3] * b1[3] + Jb[4] * b1[4] + Jb[5] * b1[5];
    const float bil = h2[0] * Gb0 + h2[1] * Gb1 + h2[2] * b1[2] + h2[3] * b1[3] + h2[4] * b1[4] + h2[5] * b1[5];
    const float q2 = h2[0] * (GC2[0] * h2[0] + GC2[1] * h2[1]) + h2[1] * (GC2[2] * h2[0] + GC2[3] * h2[1]);
    go = g1 + g2 + L[80] - 0.5f * q1 + bil + 0.5f * q2;
}

__global__ __launch_bounds__(256) void tree_kernel(float* __restrict__ ws,
                                                   const float* __restrict__ bias_scales,
                                                   const float* __restrict__ obs_noise,
                                                   const float* __restrict__ trans_noise,
                                                   const float* __restrict__ tp,
                                                   float* __restrict__ out) {
    __shared__ float lvl[12][81];
    __shared__ float J12[36];
    __shared__ float tmpA[36], tmpB[36], tmp12[12], tmp4[4], inv4[4], dump[16];
    __shared__ float shleaf[8], shsum[8], shpar[8];
    const int tid = threadIdx.x;
    const float* ybar = ws + 128;
    float* pool = ws + 16640;

    // ---- init: z-sum reduce (wave 0) + level-0 matrices + constants (thread 0) ----
    if (tid < 64) {
        const float zj = ws[tid];
        float sz = zj, sz2 = zj * zj;
        sz += __shfl_xor(sz, 2, 64);   sz2 += __shfl_xor(sz2, 2, 64);
        sz += __shfl_xor(sz, 4, 64);   sz2 += __shfl_xor(sz2, 4, 64);
        sz += __shfl_xor(sz, 8, 64);   sz2 += __shfl_xor(sz2, 8, 64);
        sz += __shfl_xor(sz, 16, 64);  sz2 += __shfl_xor(sz2, 16, 64);
        const int g = ((tid >> 5) << 1) | (tid & 1);
        if (tid == 0 || tid == 1 || tid == 32 || tid == 33) { shsum[g] = sz; shsum[4 + g] = sz2; }
    }
    if (tid == 0) {
        const float a0 = tp[0], a1 = tp[1];
        const float q = trans_noise[0] * trans_noise[0];
        const float rr = obs_noise[0] * obs_noise[0];
        shpar[0] = a0; shpar[1] = a1; shpar[2] = q; shpar[3] = rr;
        shpar[4] = bias_scales[0]; shpar[5] = bias_scales[1];
        const float c = 16.f * q / (rr * (rr + 32.f * q));
        const float s2 = 1.f / rr - 2.f * c;
        const float kpp = 4.f * q * s2;
        const float om8 = 1.f - 8.f * kpp;
        shleaf[0] = c; shleaf[1] = 1.f / rr; shleaf[2] = kpp;
        shleaf[3] = 4.f * a0; shleaf[4] = 4.f * a1;
        shleaf[5] = 2.f * 1.8378770664093453f + logf(rr) + logf(rr + 32.f * q);  // glc
        float* L = lvl[0];
        // A_top
        L[0] = 0.f; L[1] = om8 * a0; L[2] = -kpp; L[3] = -kpp; L[4] = 0.f; L[5] = 0.f;
        L[6] = om8 * a1; L[7] = 0.f; L[8] = 0.f; L[9] = 0.f; L[10] = -kpp; L[11] = -kpp;
        // C_top
        L[12] = om8 * q; L[13] = 0.f; L[14] = 0.f; L[15] = om8 * q;
        // J (6x6 sym)
        for (int i = 0; i < 36; ++i) L[16 + i] = 0.f;
        const float t2 = 2.f * s2;
        L[16 + 0] = 16.f * a1 * a1 * t2;        // J[0][0]
        L[16 + 7] = 16.f * a0 * a0 * t2;        // J[1][1]
        L[16 + 4] = L[16 + 5] = 4.f * a1 * s2;          // J[0][4], J[0][5]
        L[16 + 24] = L[16 + 30] = 4.f * a1 * s2;        // J[4][0], J[5][0]
        L[16 + 8] = L[16 + 9] = 4.f * a0 * s2;          // J[1][2], J[1][3]
        L[16 + 13] = L[16 + 19] = 4.f * a0 * s2;        // J[2][1], J[3][1]
        const float Sd = 1.f / rr - c, So = -c;
        L[16 + 14] = Sd; L[16 + 21] = Sd; L[16 + 28] = Sd; L[16 + 35] = Sd;  // diag 2..5
        L[16 + 15] = So; L[16 + 20] = So;   // J[2][3], J[3][2]
        L[16 + 29] = So; L[16 + 34] = So;   // J[4][5], J[5][4]
    }
    __syncthreads();

    for (int k = 0; k < 12; ++k) {
        float* L = lvl[k];
        // ---- S1: CJ_top (12) + 2x2 inverse/clev (lane 12, redundant CJ) ----
        if (tid < 12) {
            const int r = tid / 6, j = tid % 6;
            tmp12[tid] = L[12 + r * 2 + 0] * L[16 + j] + L[12 + r * 2 + 1] * L[16 + 6 + j];
        } else if (tid == 12) {
            const float c00 = L[12] * L[16 + 0] + L[13] * L[16 + 6];
            const float c01 = L[12] * L[16 + 1] + L[13] * L[16 + 7];
            const float c10 = L[14] * L[16 + 0] + L[15] * L[16 + 6];
            const float c11 = L[14] * L[16 + 1] + L[15] * L[16 + 7];
            const float m00 = 1.f + c00, m01 = c01, m10 = c10, m11 = 1.f + c11;
            const float det = m00 * m11 - m01 * m10;
            const float id = 1.f / det;
            inv4[0] = m11 * id; inv4[1] = -m01 * id; inv4[2] = -m10 * id; inv4[3] = m00 * id;
            L[80] = -0.5f * logf(det);
        }
        __syncthreads();
        // ---- S2: Gt(12) | GAt(12) | GC2(4) | JG(36) ----
        if (tid < 12) {
            const int r = tid / 6, j = tid % 6;
            L[52 + tid] = (j < 2) ? inv4[r * 2 + j]
                                  : -(inv4[r * 2 + 0] * tmp12[j] + inv4[r * 2 + 1] * tmp12[6 + j]);
        } else if (tid < 24) {
            const int x = tid - 12; const int r = x / 6, j = x % 6;
            const float g0 = inv4[r * 2 + 0], g1 = inv4[r * 2 + 1];
            const float gj = (j < 2) ? inv4[r * 2 + j]
                                     : -(inv4[r * 2 + 0] * tmp12[j] + inv4[r * 2 + 1] * tmp12[6 + j]);
            L[64 + x] = g0 * L[0 + j] + g1 * L[6 + j] + ((j >= 2) ? gj : 0.f);
        } else if (tid < 28) {
            const int x = tid - 24; const int r = x / 2, cc = x % 2;
            L[76 + x] = inv4[r * 2 + 0] * L[12 + cc] + inv4[r * 2 + 1] * L[14 + cc];
        } else if (tid < 64) {
            const int x = tid - 28; const int i = x / 6, j = x % 6;
            const float g0j = (j < 2) ? inv4[j] : -(inv4[0] * tmp12[j] + inv4[1] * tmp12[6 + j]);
            const float g1j = (j < 2) ? inv4[2 + j] : -(inv4[2] * tmp12[j] + inv4[3] * tmp12[6 + j]);
            tmpA[x] = L[16 + i * 6 + 0] * g0j + L[16 + i * 6 + 1] * g1j + ((j >= 2) ? L[16 + i * 6 + j] : 0.f);
        }
        __syncthreads();
        // ---- element compositions for this level ----
        const int n_out = 2048 >> k;
        const int ib = (k == 0) ? 0 : (4096 - (1 << (13 - k)));
        const int ob = 4096 - (1 << (12 - k));
        for (int i = tid; i < n_out; i += 256) {
            float b1[6], h1[6], g1, b2[6], h2[6], g2, bo[6], ho[6], go;
            if (k == 0) {
                const float4* yb = (const float4*)ybar;
                leaf_build(yb[2 * i], shleaf, b1, h1, g1);
                leaf_build(yb[2 * i + 1], shleaf, b2, h2, g2);
            } else {
                const float4* e1 = (const float4*)(pool + (size_t)(ib + 2 * i) * 16);
                float4 p0 = e1[0], p1 = e1[1], p2 = e1[2], p3 = e1[3];
                b1[0] = p0.x; b1[1] = p0.y; b1[2] = p0.z; b1[3] = p0.w; b1[4] = p1.x; b1[5] = p1.y;
                h1[0] = p1.z; h1[1] = p1.w; h1[2] = p2.x; h1[3] = p2.y; h1[4] = p2.z; h1[5] = p2.w;
                g1 = p3.x;
                const float4* e2 = (const float4*)(pool + (size_t)(ib + 2 * i + 1) * 16);
                float4 r0 = e2[0], r1 = e2[1], r2 = e2[2], r3 = e2[3];
                b2[0] = r0.x; b2[1] = r0.y; b2[2] = r0.z; b2[3] = r0.w; b2[4] = r1.x; b2[5] = r1.y;
                h2[0] = r1.z; h2[1] = r1.w; h2[2] = r2.x; h2[3] = r2.y; h2[4] = r2.z; h2[5] = r2.w;
                g2 = r3.x;
            }
            compose_el(L, b1, h1, g1, b2, h2, g2, bo, ho, go);
            float4* eo = (float4*)(pool + (size_t)(ob + i) * 16);
            eo[0] = make_float4(bo[0], bo[1], bo[2], bo[3]);
            eo[1] = make_float4(bo[4], bo[5], ho[0], ho[1]);
            eo[2] = make_float4(ho[2], ho[3], ho[4], ho[5]);
            eo[3] = make_float4(go, 0.f, 0.f, 0.f);
        }
        __syncthreads();
        // ---- S3: nA(12) | T1(4) | AtY(36) ----
        float* dA = (k < 11) ? lvl[k + 1] : dump;
        float* dC = (k < 11) ? (lvl[k + 1] + 12) : dump;
        float* dJ = (k < 11) ? (lvl[k + 1] + 16) : J12;
        if (tid < 12) {
            const int i = tid / 6, j = tid % 6;
            dA[tid] = L[i * 6 + 0] * L[64 + j] + L[i * 6 + 1] * L[64 + 6 + j] + ((j >= 2) ? L[i * 6 + j] : 0.f);
        } else if (tid < 16) {
            const int x = tid - 12; const int r = x / 2, cc = x % 2;
            tmp4[x] = L[r * 6 + 0] * L[76 + cc] + L[r * 6 + 1] * L[78 + cc];
        } else if (tid < 52) {
            const int x = tid - 16; const int i = x / 6, j = x % 6;
            tmpB[x] = L[0 + i] * tmpA[j] + L[6 + i] * tmpA[6 + j] + ((i >= 2) ? tmpA[i * 6 + j] : 0.f);
        }
        __syncthreads();
        // ---- S4: Z(36) | nC (lane 36) ----
        if (tid < 36) {
            const int i = tid / 6, j = tid % 6;
            tmpA[tid] = tmpB[i * 6 + 0] * L[j] + tmpB[i * 6 + 1] * L[6 + j] + ((j >= 2) ? tmpB[i * 6 + j] : 0.f);
        } else if (tid == 36) {
            const float X00 = tmp4[0] * L[0] + tmp4[1] * L[1];
            const float X01 = tmp4[0] * L[6] + tmp4[1] * L[7];
            const float X10 = tmp4[2] * L[0] + tmp4[3] * L[1];
            const float X11 = tmp4[2] * L[6] + tmp4[3] * L[7];
            const float xo = 0.5f * (X01 + X10);
            dC[0] = L[12] + X00; dC[1] = L[13] + xo; dC[2] = L[14] + xo; dC[3] = L[15] + X11;
        }
        __syncthreads();
        // ---- S5: nJ = J + sym(Z) ----
        if (tid < 36) {
            const int i = tid / 6, j = tid % 6;
            dJ[tid] = L[16 + tid] + 0.5f * (tmpA[i * 6 + j] + tmpA[j * 6 + i]);
        }
        __syncthreads();
    }

    // ---- final: compose prior (left) with root element, add contrasts ----
    if (tid == 0) {
        const float* re = pool + (size_t)4094 * 16;
        float hr[6];
#pragma unroll
        for (int j = 0; j < 6; ++j) hr[j] = re[6 + j];
        const float g_r = re[12];
        const float b0 = shpar[4], b1p = shpar[5];
        const float P0d[6] = {1.f, 1.f, b0, b1p, b0, b1p};
        float s[6];
#pragma unroll
        for (int i = 0; i < 6; ++i) s[i] = sqrtf(P0d[i]);
        float Mm[6][6];
#pragma unroll
        for (int i = 0; i < 6; ++i)
#pragma unroll
            for (int j = 0; j < 6; ++j)
                Mm[i][j] = ((i == j) ? 1.f : 0.f) + s[i] * s[j] * J12[i * 6 + j];
        // Cholesky (SPD since J PSD)
        float Lo[6][6];
#pragma unroll
        for (int i = 0; i < 6; ++i) {
#pragma unroll
            for (int j = 0; j <= i; ++j) {
                float sum = Mm[i][j];
#pragma unroll
                for (int m = 0; m < 6; ++m) if (m < j) sum -= Lo[i][m] * Lo[j][m];
                if (i == j) Lo[i][i] = sqrtf(sum);
                else Lo[i][j] = sum / Lo[j][j];
            }
        }
        float ldet = 0.f;
#pragma unroll
        for (int i = 0; i < 6; ++i) ldet += logf(Lo[i][i]);
        ldet *= 2.f;
        // forward solve L y = s.*hr ;  0.5*||y||^2 = 0.5 * eta' (I+P0J)^-1 P0 eta
        float yv[6];
#pragma unroll
        for (int i = 0; i < 6; ++i) {
            float sum = s[i] * hr[i];
#pragma unroll
            for (int m = 0; m < 6; ++m) if (m < i) sum -= Lo[i][m] * yv[m];
            yv[i] = sum / Lo[i][i];
        }
        float qd = 0.f;
#pragma unroll
        for (int i = 0; i < 6; ++i) qd += yv[i] * yv[i];
        double llc = (double)g_r - 0.5 * (double)ldet + 0.5 * (double)qd;

        // contrast coordinates: 15 per group, closed form (same as verified round 1)
        const float bgv[4] = {b0, b1p, b0, b1p};
        const double r = (double)shpar[3];
        const double T_ = 4096.0;
        const double LOG2PI = 1.8378770664093453;
#pragma unroll
        for (int gg = 0; gg < 4; ++gg) {
            const double b = (double)bgv[gg];
            const double sumz = (double)shsum[gg];
            const double sumz2 = (double)shsum[4 + gg];
            const double Zp = sumz2 - sumz * sumz / 16.0;
            const double Sqp = (double)ws[64 + gg] - (double)ws[68 + gg];
            llc += -0.5 * Sqp / r
                   + 0.5 * (b / (r * (r + T_ * b))) * Zp
                   - 7.5 * ((T_ - 1.0) * log(r) + log(r + T_ * b))
                   - 7.5 * T_ * LOG2PI;
        }
        out[0] = (float)llc;
    }
}

extern "C" void kernel_launch(void* const* d_in, const int* in_sizes, int n_in,
                              void* d_out, int out_size, void* d_ws, size_t ws_size,
                              hipStream_t stream) {
    const float* track            = (const float*)d_in[0];
    const float* bias_scales      = (const float*)d_in[1];
    const float* obs_noise        = (const float*)d_in[2];
    const float* trans_noise      = (const float*)d_in[3];
    const float* transition_param = (const float*)d_in[4];
    float* ws = (float*)d_ws;
    float* out = (float*)d_out;

    hipMemsetAsync(ws, 0, 512, stream);   // zero z[64] + Sq[4] + sy2[4]
    reduce_kernel<<<TT / 16, 64, 0, stream>>>(track, ws);
    tree_kernel<<<1, 256, 0, stream>>>(ws, bias_scales, obs_noise, trans_noise,
                                       transition_param, out);
}

// Round 3
// 83.900 us; speedup vs baseline: 47.1830x; 1.4168x over previous
//
#include <hip/hip_runtime.h>

#define TT 4096
#define LOG2PI 1.8378770664093453

// ws layout: 64 slots, stride 96 floats (384 B):
//   slot[b][0..63]  = per-sensor z partial (sum over block's 64 timesteps)
//   slot[b][64..67] = per-group Sq partial (sum of raw y^2)
//   slot[b][68..71] = per-group sy2 partial (sum of ybar^2)
//   slot[b][72..83] = element (b0,b1,h0..h5,g, pad x3), 16B-aligned

// Reduced per-level matrices: A=[[A2,B],[0,I]], C top-left 2x2 sym, J with
// pairwise bias-exchange structure. 23 scalars total.
struct MRed {
    float a00, a01, a10, a11;        // A2
    float b0a, b0b, b1a, b1b;        // B: row0=[b0a,b0a,b0b,b0b], row1=[b1a,b1a,b1b,b1b]
    float c0, cx, c1;                // C sym
    float j00, j01, j11;             // J top 2x2
    float ja, jb, jc, jd;            // J cross: row0=[ja,ja,jb,jb], row1=[jc,jc,jd,jd]
    float p4d, p4o, p4x, p4e, p4f;   // J4: aa-diag, aa-off, ab, bb-diag, bb-off
};

struct DRed {
    float g00, g01, g10, g11;        // G2 = inv(I + C*J2)
    float ga00, ga01, ga10, ga11;    // G2*A2
    float d0a, d0b, d1a, d1b;        // delta = G2*B + Gc  (GA cross block)
    float gc00, gc01, gc10, gc11;    // G2*C
    float clev;                      // -0.5*log det(I+C*J2)
};

struct Elem { float b0, b1, h0, h1, h2, h3, h4, h5, g; };

__device__ __forceinline__ DRed derive(const MRed& M, bool want_clev) {
    DRed D;
    const float cj00 = M.c0 * M.j00 + M.cx * M.j01;
    const float cj01 = M.c0 * M.j01 + M.cx * M.j11;
    const float cj10 = M.cx * M.j00 + M.c1 * M.j01;
    const float cj11 = M.cx * M.j01 + M.c1 * M.j11;
    const float m00 = 1.f + cj00, m01 = cj01, m10 = cj10, m11 = 1.f + cj11;
    const float det = m00 * m11 - m01 * m10;
    const float id = 1.f / det;
    D.g00 = m11 * id; D.g01 = -m01 * id; D.g10 = -m10 * id; D.g11 = m00 * id;
    D.clev = want_clev ? (-0.5f * logf(det)) : 0.f;
    const float CJa0 = M.c0 * M.ja + M.cx * M.jc, CJa1 = M.cx * M.ja + M.c1 * M.jc;
    const float CJb0 = M.c0 * M.jb + M.cx * M.jd, CJb1 = M.cx * M.jb + M.c1 * M.jd;
    const float g0a = -(D.g00 * CJa0 + D.g01 * CJa1);
    const float g1a = -(D.g10 * CJa0 + D.g11 * CJa1);
    const float g0b = -(D.g00 * CJb0 + D.g01 * CJb1);
    const float g1b = -(D.g10 * CJb0 + D.g11 * CJb1);
    D.ga00 = D.g00 * M.a00 + D.g01 * M.a10; D.ga01 = D.g00 * M.a01 + D.g01 * M.a11;
    D.ga10 = D.g10 * M.a00 + D.g11 * M.a10; D.ga11 = D.g10 * M.a01 + D.g11 * M.a11;
    D.d0a = D.g00 * M.b0a + D.g01 * M.b1a + g0a;
    D.d1a = D.g10 * M.b0a + D.g11 * M.b1a + g1a;
    D.d0b = D.g00 * M.b0b + D.g01 * M.b1b + g0b;
    D.d1b = D.g10 * M.b0b + D.g11 * M.b1b + g1b;
    D.gc00 = D.g00 * M.c0 + D.g01 * M.cx; D.gc01 = D.g00 * M.cx + D.g01 * M.c1;
    D.gc10 = D.g10 * M.c0 + D.g11 * M.cx; D.gc11 = D.g10 * M.cx + D.g11 * M.c1;
    return D;
}

__device__ __forceinline__ void mupdate(MRed& M, const DRed& D) {
    const float k00 = M.j00 * D.ga00 + M.j01 * D.ga10, k01 = M.j00 * D.ga01 + M.j01 * D.ga11;
    const float k10 = M.j01 * D.ga00 + M.j11 * D.ga10, k11 = M.j01 * D.ga01 + M.j11 * D.ga11;
    const float V0a = M.j00 * D.d0a + M.j01 * D.d1a + M.ja;
    const float V1a = M.j01 * D.d0a + M.j11 * D.d1a + M.jc;
    const float V0b = M.j00 * D.d0b + M.j01 * D.d1b + M.jb;
    const float V1b = M.j01 * D.d0b + M.j11 * D.d1b + M.jd;
    const float U0a = M.a00 * V0a + M.a10 * V1a, U1a = M.a01 * V0a + M.a11 * V1a;
    const float U0b = M.a00 * V0b + M.a10 * V1b, U1b = M.a01 * V0b + M.a11 * V1b;
    const float Ta0 = M.b0a * k00 + M.b1a * k10 + M.ja * D.ga00 + M.jc * D.ga10;
    const float Ta1 = M.b0a * k01 + M.b1a * k11 + M.ja * D.ga01 + M.jc * D.ga11;
    const float Tb0 = M.b0b * k00 + M.b1b * k10 + M.jb * D.ga00 + M.jd * D.ga10;
    const float Tb1 = M.b0b * k01 + M.b1b * k11 + M.jb * D.ga01 + M.jd * D.ga11;
    const float Eaa = M.b0a * V0a + M.b1a * V1a + M.ja * D.d0a + M.jc * D.d1a;
    const float Eab = M.b0a * V0b + M.b1a * V1b + M.ja * D.d0b + M.jc * D.d1b;
    const float Eba = M.b0b * V0a + M.b1b * V1a + M.jb * D.d0a + M.jd * D.d1a;
    const float Ebb = M.b0b * V0b + M.b1b * V1b + M.jb * D.d0b + M.jd * D.d1b;
    const float nj00 = M.j00 + (M.a00 * k00 + M.a10 * k10);
    const float nj11 = M.j11 + (M.a01 * k01 + M.a11 * k11);
    const float nj01 = M.j01 + 0.5f * ((M.a00 * k01 + M.a10 * k11) + (M.a01 * k00 + M.a11 * k10));
    const float nja = M.ja + 0.5f * (U0a + Ta0);
    const float njc = M.jc + 0.5f * (U1a + Ta1);
    const float njb = M.jb + 0.5f * (U0b + Tb0);
    const float njd = M.jd + 0.5f * (U1b + Tb1);
    const float np4d = M.p4d + Eaa, np4o = M.p4o + Eaa;
    const float np4x = M.p4x + 0.5f * (Eab + Eba);
    const float np4e = M.p4e + Ebb, np4f = M.p4f + Ebb;
    const float ta = M.a00 * D.gc00 + M.a01 * D.gc10, tb = M.a00 * D.gc01 + M.a01 * D.gc11;
    const float tc = M.a10 * D.gc00 + M.a11 * D.gc10, td = M.a10 * D.gc01 + M.a11 * D.gc11;
    const float X00 = ta * M.a00 + tb * M.a01, X01 = ta * M.a10 + tb * M.a11;
    const float X10 = tc * M.a00 + td * M.a01, X11 = tc * M.a10 + td * M.a11;
    const float nc0 = M.c0 + X00, ncx = M.cx + 0.5f * (X01 + X10), nc1 = M.c1 + X11;
    const float na00 = M.a00 * D.ga00 + M.a01 * D.ga10, na01 = M.a00 * D.ga01 + M.a01 * D.ga11;
    const float na10 = M.a10 * D.ga00 + M.a11 * D.ga10, na11 = M.a10 * D.ga01 + M.a11 * D.ga11;
    const float nb0a = M.a00 * D.d0a + M.a01 * D.d1a + M.b0a;
    const float nb1a = M.a10 * D.d0a + M.a11 * D.d1a + M.b1a;
    const float nb0b = M.a00 * D.d0b + M.a01 * D.d1b + M.b0b;
    const float nb1b = M.a10 * D.d0b + M.a11 * D.d1b + M.b1b;
    M.a00 = na00; M.a01 = na01; M.a10 = na10; M.a11 = na11;
    M.b0a = nb0a; M.b0b = nb0b; M.b1a = nb1a; M.b1b = nb1b;
    M.c0 = nc0; M.cx = ncx; M.c1 = nc1;
    M.j00 = nj00; M.j01 = nj01; M.j11 = nj11;
    M.ja = nja; M.jb = njb; M.jc = njc; M.jd = njd;
    M.p4d = np4d; M.p4o = np4o; M.p4x = np4x; M.p4e = np4e; M.p4f = np4f;
}

__device__ __forceinline__ Elem shfl_elem(const Elem& e, int src) {
    Elem r;
    r.b0 = __shfl(e.b0, src, 64); r.b1 = __shfl(e.b1, src, 64);
    r.h0 = __shfl(e.h0, src, 64); r.h1 = __shfl(e.h1, src, 64);
    r.h2 = __shfl(e.h2, src, 64); r.h3 = __shfl(e.h3, src, 64);
    r.h4 = __shfl(e.h4, src, 64); r.h5 = __shfl(e.h5, src, 64);
    r.g  = __shfl(e.g,  src, 64);
    return r;
}

__device__ __forceinline__ Elem compose_red(const MRed& M, const DRed& D,
                                            const Elem& e1, const Elem& e2) {
    const float Jb0 = M.j00 * e1.b0 + M.j01 * e1.b1;
    const float Jb1 = M.j01 * e1.b0 + M.j11 * e1.b1;
    const float Jba = M.ja * e1.b0 + M.jc * e1.b1;
    const float Jbb = M.jb * e1.b0 + M.jd * e1.b1;
    const float Gb0 = D.g00 * e1.b0 + D.g01 * e1.b1;
    const float Gb1 = D.g10 * e1.b0 + D.g11 * e1.b1;
    const float t0 = e1.b0 + M.c0 * e2.h0 + M.cx * e2.h1;
    const float t1 = e1.b1 + M.cx * e2.h0 + M.c1 * e2.h1;
    const float u0 = D.g00 * t0 + D.g01 * t1;
    const float u1 = D.g10 * t0 + D.g11 * t1;
    Elem o;
    o.b0 = M.a00 * u0 + M.a01 * u1 + e2.b0;
    o.b1 = M.a10 * u0 + M.a11 * u1 + e2.b1;
    const float w0 = e2.h0 - Jb0, w1 = e2.h1 - Jb1;
    const float w2 = e2.h2 - Jba, w3 = e2.h3 - Jba;
    const float w4 = e2.h4 - Jbb, w5 = e2.h5 - Jbb;
    o.h0 = e1.h0 + w0 * D.ga00 + w1 * D.ga10;
    o.h1 = e1.h1 + w0 * D.ga01 + w1 * D.ga11;
    o.h2 = e1.h2 + w0 * D.d0a + w1 * D.d1a + w2;
    o.h3 = e1.h3 + w0 * D.d0a + w1 * D.d1a + w3;
    o.h4 = e1.h4 + w0 * D.d0b + w1 * D.d1b + w4;
    o.h5 = e1.h5 + w0 * D.d0b + w1 * D.d1b + w5;
    const float q1 = Jb0 * Gb0 + Jb1 * Gb1;
    const float bil = e2.h0 * Gb0 + e2.h1 * Gb1;
    const float q2 = e2.h0 * (D.gc00 * e2.h0 + D.gc01 * e2.h1)
                   + e2.h1 * (D.gc10 * e2.h0 + D.gc11 * e2.h1);
    o.g = e1.g + e2.g + D.clev - 0.5f * q1 + bil + 0.5f * q2;
    return o;
}

__device__ __forceinline__ MRed m_init(float a0, float a1, float q, float rr,
                                       float& c, float& kpp, float& glc) {
    c = 16.f * q / (rr * (rr + 32.f * q));
    const float s2 = 1.f / rr - 2.f * c;
    kpp = 4.f * q * s2;
    const float om8 = 1.f - 8.f * kpp;
    glc = 2.f * (float)LOG2PI + logf(rr) + logf(rr + 32.f * q);
    MRed M;
    M.a00 = 0.f; M.a01 = om8 * a0; M.a10 = om8 * a1; M.a11 = 0.f;
    M.b0a = -kpp; M.b0b = 0.f; M.b1a = 0.f; M.b1b = -kpp;
    M.c0 = om8 * q; M.cx = 0.f; M.c1 = om8 * q;
    M.j00 = 32.f * a1 * a1 * s2; M.j01 = 0.f; M.j11 = 32.f * a0 * a0 * s2;
    M.ja = 0.f; M.jb = 4.f * a1 * s2; M.jc = 4.f * a0 * s2; M.jd = 0.f;
    const float Sd = 1.f / rr - c, So = -c;
    M.p4d = Sd; M.p4o = So; M.p4x = 0.f; M.p4e = Sd; M.p4f = So;
    return M;
}

__global__ __launch_bounds__(256) void leaf_kernel(const float* __restrict__ track,
                                                   float* __restrict__ ws,
                                                   const float* __restrict__ obs_noise,
                                                   const float* __restrict__ trans_noise,
                                                   const float* __restrict__ tp) {
    __shared__ float zp[256];
    __shared__ float sqp[16], syp[16];
    __shared__ float4 ybar_s[64];
    const int tid = threadIdx.x, w = tid >> 6, l = tid & 63, b = blockIdx.x;
    const float a0 = tp[0], a1 = tp[1];
    const float q = trans_noise[0] * trans_noise[0];
    const float rr = obs_noise[0] * obs_noise[0];
    const float* base = track + (size_t)b * 64 * 64;
    const int g = ((l >> 5) << 1) | (l & 1);
    const bool writer = (l == 0) || (l == 1) || (l == 32) || (l == 33);
    float accz = 0.f, accsq = 0.f, accy2 = 0.f;
#pragma unroll
    for (int it = 0; it < 16; ++it) {
        const int tl = it * 4 + w;
        const float v = base[tl * 64 + l];
        accz += v; accsq += v * v;
        float s = v;
        s += __shfl_xor(s, 2, 64); s += __shfl_xor(s, 4, 64);
        s += __shfl_xor(s, 8, 64); s += __shfl_xor(s, 16, 64);
        if (writer) {
            const float yb = 0.25f * s;
            ((float*)&ybar_s[tl])[g] = yb;
            accy2 += yb * yb;
        }
    }
    zp[tid] = accz;
    float s2 = accsq;
    s2 += __shfl_xor(s2, 2, 64); s2 += __shfl_xor(s2, 4, 64);
    s2 += __shfl_xor(s2, 8, 64); s2 += __shfl_xor(s2, 16, 64);
    if (writer) { sqp[w * 4 + g] = s2; syp[w * 4 + g] = accy2; }
    __syncthreads();
    if (w != 0) return;

    float* slot = ws + b * 96;
    slot[l] = zp[l] + zp[64 + l] + zp[128 + l] + zp[192 + l];
    if (l < 4) {
        slot[64 + l] = sqp[l] + sqp[4 + l] + sqp[8 + l] + sqp[12 + l];
    } else if (l < 8) {
        const int gg = l - 4;
        slot[68 + gg] = syp[gg] + syp[4 + gg] + syp[8 + gg] + syp[12 + gg];
    }

    // leaf build (lane l owns timestep t = 64*b + l)
    float c, kpp, glc;
    MRed M = m_init(a0, a1, q, rr, c, kpp, glc);
    const float4 y = ybar_s[l];
    const float irr = 1.f / rr;
    const float bs0 = y.x + y.y, bs1 = y.z + y.w;
    const float v0 = y.x * irr - c * bs0, v1 = y.y * irr - c * bs0;
    const float v2 = y.z * irr - c * bs1, v3 = y.w * irr - c * bs1;
    Elem e;
    e.b0 = kpp * bs0; e.b1 = kpp * bs1;
    e.h0 = 4.f * a1 * (v2 + v3); e.h1 = 4.f * a0 * (v0 + v1);
    e.h2 = v0; e.h3 = v1; e.h4 = v2; e.h5 = v3;
    e.g = -0.5f * (y.x * v0 + y.y * v1 + y.z * v2 + y.w * v3) - glc;

    // local tree: 6 levels, shuffle-only (single wave, no barriers)
#pragma unroll
    for (int k = 0; k < 6; ++k) {
        const DRed D = derive(M, true);
        const int sA = (2 * l) & 63, sB = (2 * l + 1) & 63;
        const Elem e1 = shfl_elem(e, sA);
        const Elem e2 = shfl_elem(e, sB);
        e = compose_red(M, D, e1, e2);
        mupdate(M, D);
    }
    if (l == 0) {
        float4* eo = (float4*)(slot + 72);
        eo[0] = make_float4(e.b0, e.b1, e.h0, e.h1);
        eo[1] = make_float4(e.h2, e.h3, e.h4, e.h5);
        eo[2] = make_float4(e.g, 0.f, 0.f, 0.f);
    }
}

__global__ __launch_bounds__(64) void final_kernel(const float* __restrict__ ws,
                                                   const float* __restrict__ bias_scales,
                                                   const float* __restrict__ obs_noise,
                                                   const float* __restrict__ trans_noise,
                                                   const float* __restrict__ tp,
                                                   float* __restrict__ out) {
    __shared__ float cst[16];
    const int l = threadIdx.x;
    const float a0 = tp[0], a1 = tp[1];
    const float q = trans_noise[0] * trans_noise[0];
    const float rr = obs_noise[0] * obs_noise[0];
    const float bsc0 = bias_scales[0], bsc1 = bias_scales[1];
    float c, kpp, glc;
    MRed M = m_init(a0, a1, q, rr, c, kpp, glc);
    // advance matrix chain through the 6 leaf-local levels (no compose here)
#pragma unroll
    for (int k = 0; k < 6; ++k) { const DRed D = derive(M, false); mupdate(M, D); }

    // reduce per-block scalar partials
    float zacc = 0.f;
#pragma unroll 8
    for (int b = 0; b < 64; ++b) zacc += ws[b * 96 + l];
    float aux = 0.f;
    if (l < 8) {
        const int off = 64 + l;   // l<4: Sq[g]; l=4..7: sy2[g]
#pragma unroll 8
        for (int b = 0; b < 64; ++b) aux += ws[b * 96 + off];
    }

    // read the 64 block elements (lane l <- block l)
    const float4* ep = (const float4*)(ws + l * 96 + 72);
    const float4 p0 = ep[0], p1 = ep[1], p2 = ep[2];
    Elem e;
    e.b0 = p0.x; e.b1 = p0.y;
    e.h0 = p0.z; e.h1 = p0.w; e.h2 = p1.x; e.h3 = p1.y; e.h4 = p1.z; e.h5 = p1.w;
    e.g = p2.x;

    // final 6 tree levels via shuffles
#pragma unroll
    for (int k = 0; k < 6; ++k) {
        const DRed D = derive(M, true);
        const int sA = (2 * l) & 63, sB = (2 * l + 1) & 63;
        const Elem e1 = shfl_elem(e, sA);
        const Elem e2 = shfl_elem(e, sB);
        e = compose_red(M, D, e1, e2);
        mupdate(M, D);
    }

    // group sums of z for the contrast terms
    float sz = zacc, sz2 = zacc * zacc;
    sz += __shfl_xor(sz, 2, 64);  sz2 += __shfl_xor(sz2, 2, 64);
    sz += __shfl_xor(sz, 4, 64);  sz2 += __shfl_xor(sz2, 4, 64);
    sz += __shfl_xor(sz, 8, 64);  sz2 += __shfl_xor(sz2, 8, 64);
    sz += __shfl_xor(sz, 16, 64); sz2 += __shfl_xor(sz2, 16, 64);
    const int g = ((l >> 5) << 1) | (l & 1);
    if (l == 0 || l == 1 || l == 32 || l == 33) { cst[g] = sz; cst[4 + g] = sz2; }
    if (l < 8) cst[8 + l] = aux;   // 8..11 = Sq[g], 12..15 = sy2[g]
    __syncthreads();

    if (l == 0) {
        // reconstruct root J (6x6) from reduced form
        float J6[6][6];
        J6[0][0] = M.j00; J6[0][1] = J6[1][0] = M.j01; J6[1][1] = M.j11;
        J6[0][2] = J6[0][3] = J6[2][0] = J6[3][0] = M.ja;
        J6[0][4] = J6[0][5] = J6[4][0] = J6[5][0] = M.jb;
        J6[1][2] = J6[1][3] = J6[2][1] = J6[3][1] = M.jc;
        J6[1][4] = J6[1][5] = J6[4][1] = J6[5][1] = M.jd;
        J6[2][2] = J6[3][3] = M.p4d; J6[2][3] = J6[3][2] = M.p4o;
        J6[2][4] = J6[2][5] = J6[3][4] = J6[3][5] = M.p4x;
        J6[4][2] = J6[5][2] = J6[4][3] = J6[5][3] = M.p4x;
        J6[4][4] = J6[5][5] = M.p4e; J6[4][5] = J6[5][4] = M.p4f;
        const float s[6] = {1.f, 1.f, sqrtf(bsc0), sqrtf(bsc1), sqrtf(bsc0), sqrtf(bsc1)};
        float Mm[6][6];
#pragma unroll
        for (int i = 0; i < 6; ++i)
#pragma unroll
            for (int j = 0; j < 6; ++j)
                Mm[i][j] = ((i == j) ? 1.f : 0.f) + s[i] * s[j] * J6[i][j];
        float Lo[6][6];
#pragma unroll
        for (int i = 0; i < 6; ++i) {
#pragma unroll
            for (int j = 0; j <= i; ++j) {
                float sum = Mm[i][j];
#pragma unroll
                for (int m = 0; m < 6; ++m) if (m < j) sum -= Lo[i][m] * Lo[j][m];
                if (i == j) Lo[i][i] = sqrtf(sum);
                else Lo[i][j] = sum / Lo[j][j];
            }
        }
        float ldet = 0.f;
#pragma unroll
        for (int i = 0; i < 6; ++i) ldet += logf(Lo[i][i]);
        ldet *= 2.f;
        const float hr[6] = {e.h0, e.h1, e.h2, e.h3, e.h4, e.h5};
        float yv[6];
#pragma unroll
        for (int i = 0; i < 6; ++i) {
            float sum = s[i] * hr[i];
#pragma unroll
            for (int m = 0; m < 6; ++m) if (m < i) sum -= Lo[i][m] * yv[m];
            yv[i] = sum / Lo[i][i];
        }
        float qd = 0.f;
#pragma unroll
        for (int i = 0; i < 6; ++i) qd += yv[i] * yv[i];
        double llc = (double)e.g - 0.5 * (double)ldet + 0.5 * (double)qd;

        // contrast coordinates: 15 per group, closed form (verified rounds 1-2)
        const float bgv[4] = {bsc0, bsc1, bsc0, bsc1};
        const double r = (double)rr;
        const double T_ = 4096.0;
#pragma unroll
        for (int gg = 0; gg < 4; ++gg) {
            const double b = (double)bgv[gg];
            const double sumz = (double)cst[gg];
            const double sumz2 = (double)cst[4 + gg];
            const double Zp = sumz2 - sumz * sumz / 16.0;
            const double Sqp = (double)cst[8 + gg] - (double)cst[12 + gg];
            llc += -0.5 * Sqp / r
                   + 0.5 * (b / (r * (r + T_ * b))) * Zp
                   - 7.5 * ((T_ - 1.0) * log(r) + log(r + T_ * b))
                   - 7.5 * T_ * LOG2PI;
        }
        out[0] = (float)llc;
    }
}

extern "C" void kernel_launch(void* const* d_in, const int* in_sizes, int n_in,
                              void* d_out, int out_size, void* d_ws, size_t ws_size,
                              hipStream_t stream) {
    const float* track            = (const float*)d_in[0];
    const float* bias_scales      = (const float*)d_in[1];
    const float* obs_noise        = (const float*)d_in[2];
    const float* trans_noise      = (const float*)d_in[3];
    const float* transition_param = (const float*)d_in[4];
    float* ws = (float*)d_ws;
    float* out = (float*)d_out;

    leaf_kernel<<<64, 256, 0, stream>>>(track, ws, obs_noise, trans_noise, transition_param);
    final_kernel<<<1, 64, 0, stream>>>(ws, bias_scales, obs_noise, trans_noise,
                                       transition_param, out);
}

// Round 4
// 82.971 us; speedup vs baseline: 47.7113x; 1.0112x over previous
//
#include <hip/hip_runtime.h>

#define TT 4096
#define LOG2PI 1.8378770664093453

// ws layout: 64 slots, stride 96 floats (384 B):
//   slot[b][0..63]  = per-sensor z partial (sum over block's 64 timesteps)
//   slot[b][64..67] = per-group Sq partial (sum of raw y^2)
//   slot[b][68..71] = per-group sy2 partial (sum of ybar^2)
//   slot[b][72..83] = element (b0,b1,h0..h5,g, pad x3), 16B-aligned
// counter (int) at float index 6144 (byte 24576), zeroed each call by memset node.

struct MRed {
    float a00, a01, a10, a11;        // A2
    float b0a, b0b, b1a, b1b;        // B: row0=[b0a,b0a,b0b,b0b], row1=[b1a,b1a,b1b,b1b]
    float c0, cx, c1;                // C sym
    float j00, j01, j11;             // J top 2x2
    float ja, jb, jc, jd;            // J cross
    float p4d, p4o, p4x, p4e, p4f;   // J4 block
};

struct DRed {
    float g00, g01, g10, g11;        // G2 = inv(I + C*J2)
    float ga00, ga01, ga10, ga11;    // G2*A2
    float d0a, d0b, d1a, d1b;        // delta
    float gc00, gc01, gc10, gc11;    // G2*C
    float clev;
};

struct Elem { float b0, b1, h0, h1, h2, h3, h4, h5, g; };

__device__ __forceinline__ DRed derive(const MRed& M, bool want_clev) {
    DRed D;
    const float cj00 = M.c0 * M.j00 + M.cx * M.j01;
    const float cj01 = M.c0 * M.j01 + M.cx * M.j11;
    const float cj10 = M.cx * M.j00 + M.c1 * M.j01;
    const float cj11 = M.cx * M.j01 + M.c1 * M.j11;
    const float m00 = 1.f + cj00, m01 = cj01, m10 = cj10, m11 = 1.f + cj11;
    const float det = m00 * m11 - m01 * m10;
    const float id = 1.f / det;
    D.g00 = m11 * id; D.g01 = -m01 * id; D.g10 = -m10 * id; D.g11 = m00 * id;
    D.clev = want_clev ? (-0.5f * logf(det)) : 0.f;
    const float CJa0 = M.c0 * M.ja + M.cx * M.jc, CJa1 = M.cx * M.ja + M.c1 * M.jc;
    const float CJb0 = M.c0 * M.jb + M.cx * M.jd, CJb1 = M.cx * M.jb + M.c1 * M.jd;
    const float g0a = -(D.g00 * CJa0 + D.g01 * CJa1);
    const float g1a = -(D.g10 * CJa0 + D.g11 * CJa1);
    const float g0b = -(D.g00 * CJb0 + D.g01 * CJb1);
    const float g1b = -(D.g10 * CJb0 + D.g11 * CJb1);
    D.ga00 = D.g00 * M.a00 + D.g01 * M.a10; D.ga01 = D.g00 * M.a01 + D.g01 * M.a11;
    D.ga10 = D.g10 * M.a00 + D.g11 * M.a10; D.ga11 = D.g10 * M.a01 + D.g11 * M.a11;
    D.d0a = D.g00 * M.b0a + D.g01 * M.b1a + g0a;
    D.d1a = D.g10 * M.b0a + D.g11 * M.b1a + g1a;
    D.d0b = D.g00 * M.b0b + D.g01 * M.b1b + g0b;
    D.d1b = D.g10 * M.b0b + D.g11 * M.b1b + g1b;
    D.gc00 = D.g00 * M.c0 + D.g01 * M.cx; D.gc01 = D.g00 * M.cx + D.g01 * M.c1;
    D.gc10 = D.g10 * M.c0 + D.g11 * M.cx; D.gc11 = D.g10 * M.cx + D.g11 * M.c1;
    return D;
}

__device__ __forceinline__ void mupdate(MRed& M, const DRed& D) {
    const float k00 = M.j00 * D.ga00 + M.j01 * D.ga10, k01 = M.j00 * D.ga01 + M.j01 * D.ga11;
    const float k10 = M.j01 * D.ga00 + M.j11 * D.ga10, k11 = M.j01 * D.ga01 + M.j11 * D.ga11;
    const float V0a = M.j00 * D.d0a + M.j01 * D.d1a + M.ja;
    const float V1a = M.j01 * D.d0a + M.j11 * D.d1a + M.jc;
    const float V0b = M.j00 * D.d0b + M.j01 * D.d1b + M.jb;
    const float V1b = M.j01 * D.d0b + M.j11 * D.d1b + M.jd;
    const float U0a = M.a00 * V0a + M.a10 * V1a, U1a = M.a01 * V0a + M.a11 * V1a;
    const float U0b = M.a00 * V0b + M.a10 * V1b, U1b = M.a01 * V0b + M.a11 * V1b;
    const float Ta0 = M.b0a * k00 + M.b1a * k10 + M.ja * D.ga00 + M.jc * D.ga10;
    const float Ta1 = M.b0a * k01 + M.b1a * k11 + M.ja * D.ga01 + M.jc * D.ga11;
    const float Tb0 = M.b0b * k00 + M.b1b * k10 + M.jb * D.ga00 + M.jd * D.ga10;
    const float Tb1 = M.b0b * k01 + M.b1b * k11 + M.jb * D.ga01 + M.jd * D.ga11;
    const float Eaa = M.b0a * V0a + M.b1a * V1a + M.ja * D.d0a + M.jc * D.d1a;
    const float Eab = M.b0a * V0b + M.b1a * V1b + M.ja * D.d0b + M.jc * D.d1b;
    const float Eba = M.b0b * V0a + M.b1b * V1a + M.jb * D.d0a + M.jd * D.d1a;
    const float Ebb = M.b0b * V0b + M.b1b * V1b + M.jb * D.d0b + M.jd * D.d1b;
    const float nj00 = M.j00 + (M.a00 * k00 + M.a10 * k10);
    const float nj11 = M.j11 + (M.a01 * k01 + M.a11 * k11);
    const float nj01 = M.j01 + 0.5f * ((M.a00 * k01 + M.a10 * k11) + (M.a01 * k00 + M.a11 * k10));
    const float nja = M.ja + 0.5f * (U0a + Ta0);
    const float njc = M.jc + 0.5f * (U1a + Ta1);
    const float njb = M.jb + 0.5f * (U0b + Tb0);
    const float njd = M.jd + 0.5f * (U1b + Tb1);
    const float np4d = M.p4d + Eaa, np4o = M.p4o + Eaa;
    const float np4x = M.p4x + 0.5f * (Eab + Eba);
    const float np4e = M.p4e + Ebb, np4f = M.p4f + Ebb;
    const float ta = M.a00 * D.gc00 + M.a01 * D.gc10, tb = M.a00 * D.gc01 + M.a01 * D.gc11;
    const float tc = M.a10 * D.gc00 + M.a11 * D.gc10, td = M.a10 * D.gc01 + M.a11 * D.gc11;
    const float X00 = ta * M.a00 + tb * M.a01, X01 = ta * M.a10 + tb * M.a11;
    const float X10 = tc * M.a00 + td * M.a01, X11 = tc * M.a10 + td * M.a11;
    const float nc0 = M.c0 + X00, ncx = M.cx + 0.5f * (X01 + X10), nc1 = M.c1 + X11;
    const float na00 = M.a00 * D.ga00 + M.a01 * D.ga10, na01 = M.a00 * D.ga01 + M.a01 * D.ga11;
    const float na10 = M.a10 * D.ga00 + M.a11 * D.ga10, na11 = M.a10 * D.ga01 + M.a11 * D.ga11;
    const float nb0a = M.a00 * D.d0a + M.a01 * D.d1a + M.b0a;
    const float nb1a = M.a10 * D.d0a + M.a11 * D.d1a + M.b1a;
    const float nb0b = M.a00 * D.d0b + M.a01 * D.d1b + M.b0b;
    const float nb1b = M.a10 * D.d0b + M.a11 * D.d1b + M.b1b;
    M.a00 = na00; M.a01 = na01; M.a10 = na10; M.a11 = na11;
    M.b0a = nb0a; M.b0b = nb0b; M.b1a = nb1a; M.b1b = nb1b;
    M.c0 = nc0; M.cx = ncx; M.c1 = nc1;
    M.j00 = nj00; M.j01 = nj01; M.j11 = nj11;
    M.ja = nja; M.jb = njb; M.jc = njc; M.jd = njd;
    M.p4d = np4d; M.p4o = np4o; M.p4x = np4x; M.p4e = np4e; M.p4f = np4f;
}

__device__ __forceinline__ Elem shfl_elem(const Elem& e, int src) {
    Elem r;
    r.b0 = __shfl(e.b0, src, 64); r.b1 = __shfl(e.b1, src, 64);
    r.h0 = __shfl(e.h0, src, 64); r.h1 = __shfl(e.h1, src, 64);
    r.h2 = __shfl(e.h2, src, 64); r.h3 = __shfl(e.h3, src, 64);
    r.h4 = __shfl(e.h4, src, 64); r.h5 = __shfl(e.h5, src, 64);
    r.g  = __shfl(e.g,  src, 64);
    return r;
}

__device__ __forceinline__ Elem compose_red(const MRed& M, const DRed& D,
                                            const Elem& e1, const Elem& e2) {
    const float Jb0 = M.j00 * e1.b0 + M.j01 * e1.b1;
    const float Jb1 = M.j01 * e1.b0 + M.j11 * e1.b1;
    const float Jba = M.ja * e1.b0 + M.jc * e1.b1;
    const float Jbb = M.jb * e1.b0 + M.jd * e1.b1;
    const float Gb0 = D.g00 * e1.b0 + D.g01 * e1.b1;
    const float Gb1 = D.g10 * e1.b0 + D.g11 * e1.b1;
    const float t0 = e1.b0 + M.c0 * e2.h0 + M.cx * e2.h1;
    const float t1 = e1.b1 + M.cx * e2.h0 + M.c1 * e2.h1;
    const float u0 = D.g00 * t0 + D.g01 * t1;
    const float u1 = D.g10 * t0 + D.g11 * t1;
    Elem o;
    o.b0 = M.a00 * u0 + M.a01 * u1 + e2.b0;
    o.b1 = M.a10 * u0 + M.a11 * u1 + e2.b1;
    const float w0 = e2.h0 - Jb0, w1 = e2.h1 - Jb1;
    const float w2 = e2.h2 - Jba, w3 = e2.h3 - Jba;
    const float w4 = e2.h4 - Jbb, w5 = e2.h5 - Jbb;
    o.h0 = e1.h0 + w0 * D.ga00 + w1 * D.ga10;
    o.h1 = e1.h1 + w0 * D.ga01 + w1 * D.ga11;
    o.h2 = e1.h2 + w0 * D.d0a + w1 * D.d1a + w2;
    o.h3 = e1.h3 + w0 * D.d0a + w1 * D.d1a + w3;
    o.h4 = e1.h4 + w0 * D.d0b + w1 * D.d1b + w4;
    o.h5 = e1.h5 + w0 * D.d0b + w1 * D.d1b + w5;
    const float q1 = Jb0 * Gb0 + Jb1 * Gb1;
    const float bil = e2.h0 * Gb0 + e2.h1 * Gb1;
    const float q2 = e2.h0 * (D.gc00 * e2.h0 + D.gc01 * e2.h1)
                   + e2.h1 * (D.gc10 * e2.h0 + D.gc11 * e2.h1);
    o.g = e1.g + e2.g + D.clev - 0.5f * q1 + bil + 0.5f * q2;
    return o;
}

__device__ __forceinline__ MRed m_init(float a0, float a1, float q, float rr,
                                       float& c, float& kpp, float& glc) {
    c = 16.f * q / (rr * (rr + 32.f * q));
    const float s2 = 1.f / rr - 2.f * c;
    kpp = 4.f * q * s2;
    const float om8 = 1.f - 8.f * kpp;
    glc = 2.f * (float)LOG2PI + logf(rr) + logf(rr + 32.f * q);
    MRed M;
    M.a00 = 0.f; M.a01 = om8 * a0; M.a10 = om8 * a1; M.a11 = 0.f;
    M.b0a = -kpp; M.b0b = 0.f; M.b1a = 0.f; M.b1b = -kpp;
    M.c0 = om8 * q; M.cx = 0.f; M.c1 = om8 * q;
    M.j00 = 32.f * a1 * a1 * s2; M.j01 = 0.f; M.j11 = 32.f * a0 * a0 * s2;
    M.ja = 0.f; M.jb = 4.f * a1 * s2; M.jc = 4.f * a0 * s2; M.jd = 0.f;
    const float Sd = 1.f / rr - c, So = -c;
    M.p4d = Sd; M.p4o = So; M.p4x = 0.f; M.p4e = Sd; M.p4f = So;
    return M;
}

__global__ __launch_bounds__(256) void fused_kernel(const float* __restrict__ track,
                                                    float* __restrict__ ws,
                                                    int* __restrict__ counter,
                                                    const float* __restrict__ bias_scales,
                                                    const float* __restrict__ obs_noise,
                                                    const float* __restrict__ trans_noise,
                                                    const float* __restrict__ tp,
                                                    float* __restrict__ out) {
    __shared__ float zp[256];
    __shared__ float sqp[16], syp[16];
    __shared__ float4 ybar_s[64];
    __shared__ int is_last;
    const int tid = threadIdx.x, w = tid >> 6, l = tid & 63, b = blockIdx.x;
    const float a0 = tp[0], a1 = tp[1];
    const float q = trans_noise[0] * trans_noise[0];
    const float rr = obs_noise[0] * obs_noise[0];
    const float* base = track + (size_t)b * 64 * 64;
    const int g = ((l >> 5) << 1) | (l & 1);
    const bool writer = (l == 0) || (l == 1) || (l == 32) || (l == 33);
    float accz = 0.f, accsq = 0.f, accy2 = 0.f;
#pragma unroll
    for (int it = 0; it < 16; ++it) {
        const int tl = it * 4 + w;
        const float v = base[tl * 64 + l];
        accz += v; accsq += v * v;
        float s = v;
        s += __shfl_xor(s, 2, 64); s += __shfl_xor(s, 4, 64);
        s += __shfl_xor(s, 8, 64); s += __shfl_xor(s, 16, 64);
        if (writer) {
            const float yb = 0.25f * s;
            ((float*)&ybar_s[tl])[g] = yb;
            accy2 += yb * yb;
        }
    }
    zp[tid] = accz;
    float s2 = accsq;
    s2 += __shfl_xor(s2, 2, 64); s2 += __shfl_xor(s2, 4, 64);
    s2 += __shfl_xor(s2, 8, 64); s2 += __shfl_xor(s2, 16, 64);
    if (writer) { sqp[w * 4 + g] = s2; syp[w * 4 + g] = accy2; }
    __syncthreads();

    float c, kpp, glc;
    MRed M = m_init(a0, a1, q, rr, c, kpp, glc);

    if (w == 0) {
        float* slot = ws + b * 96;
        slot[l] = zp[l] + zp[64 + l] + zp[128 + l] + zp[192 + l];
        if (l < 4) {
            slot[64 + l] = sqp[l] + sqp[4 + l] + sqp[8 + l] + sqp[12 + l];
        } else if (l < 8) {
            const int gg = l - 4;
            slot[68 + gg] = syp[gg] + syp[4 + gg] + syp[8 + gg] + syp[12 + gg];
        }
        // leaf build (lane l owns timestep t = 64*b + l)
        const float4 y = ybar_s[l];
        const float irr = 1.f / rr;
        const float bs0 = y.x + y.y, bs1 = y.z + y.w;
        const float v0 = y.x * irr - c * bs0, v1 = y.y * irr - c * bs0;
        const float v2 = y.z * irr - c * bs1, v3 = y.w * irr - c * bs1;
        Elem e;
        e.b0 = kpp * bs0; e.b1 = kpp * bs1;
        e.h0 = 4.f * a1 * (v2 + v3); e.h1 = 4.f * a0 * (v0 + v1);
        e.h2 = v0; e.h3 = v1; e.h4 = v2; e.h5 = v3;
        e.g = -0.5f * (y.x * v0 + y.y * v1 + y.z * v2 + y.w * v3) - glc;
        // local tree: 6 levels, shuffle-only
#pragma unroll
        for (int k = 0; k < 6; ++k) {
            const DRed D = derive(M, true);
            const Elem e1 = shfl_elem(e, (2 * l) & 63);
            const Elem e2 = shfl_elem(e, (2 * l + 1) & 63);
            e = compose_red(M, D, e1, e2);
            mupdate(M, D);
        }
        if (l == 0) {
            float4* eo = (float4*)(slot + 72);
            eo[0] = make_float4(e.b0, e.b1, e.h0, e.h1);
            eo[1] = make_float4(e.h2, e.h3, e.h4, e.h5);
            eo[2] = make_float4(e.g, 0.f, 0.f, 0.f);
        }
    }

    // release our slot, signal; last block continues.
    __threadfence();
    if (tid == 0) is_last = (atomicAdd(counter, 1) == 63);
    __syncthreads();
    if (!is_last) return;
    if (w != 0) return;          // no barriers beyond this point
    __threadfence();             // acquire

    // ---- final stage: wave 0 only ----
    float zl = 0.f;
#pragma unroll 8
    for (int bb = 0; bb < 64; ++bb) zl += ws[bb * 96 + l];

    const float4* sp = (const float4*)(ws + l * 96 + 64);
    const float4 q0 = sp[0], q1 = sp[1];           // aux: Sq[0..3], sy2[0..3]
    const float4 p0 = sp[2], p1 = sp[3], p2 = sp[4];  // element of block l
    Elem e;
    e.b0 = p0.x; e.b1 = p0.y;
    e.h0 = p0.z; e.h1 = p0.w; e.h2 = p1.x; e.h3 = p1.y; e.h4 = p1.z; e.h5 = p1.w;
    e.g = p2.x;

    // total Sq/sy2 across blocks: full 64-lane sum of each of the 8 values
    float axv[8] = {q0.x, q0.y, q0.z, q0.w, q1.x, q1.y, q1.z, q1.w};
#pragma unroll
    for (int i = 0; i < 8; ++i) {
        float t = axv[i];
        t += __shfl_xor(t, 1, 64); t += __shfl_xor(t, 2, 64); t += __shfl_xor(t, 4, 64);
        t += __shfl_xor(t, 8, 64); t += __shfl_xor(t, 16, 64); t += __shfl_xor(t, 32, 64);
        axv[i] = t;
    }

    // final 6 tree levels (M already advanced through the 6 local levels)
#pragma unroll
    for (int k = 0; k < 6; ++k) {
        const DRed D = derive(M, true);
        const Elem e1 = shfl_elem(e, (2 * l) & 63);
        const Elem e2 = shfl_elem(e, (2 * l + 1) & 63);
        e = compose_red(M, D, e1, e2);
        mupdate(M, D);
    }

    // group sums of z (per-sensor totals) for the contrast terms
    float sz = zl, sz2 = zl * zl;
    sz += __shfl_xor(sz, 2, 64);  sz2 += __shfl_xor(sz2, 2, 64);
    sz += __shfl_xor(sz, 4, 64);  sz2 += __shfl_xor(sz2, 4, 64);
    sz += __shfl_xor(sz, 8, 64);  sz2 += __shfl_xor(sz2, 8, 64);
    sz += __shfl_xor(sz, 16, 64); sz2 += __shfl_xor(sz2, 16, 64);
    // groups live at lanes 0(g0), 1(g1), 32(g2), 33(g3)
    float csz[4], csz2[4];
    csz[0] = __shfl(sz, 0, 64);  csz[1] = __shfl(sz, 1, 64);
    csz[2] = __shfl(sz, 32, 64); csz[3] = __shfl(sz, 33, 64);
    csz2[0] = __shfl(sz2, 0, 64);  csz2[1] = __shfl(sz2, 1, 64);
    csz2[2] = __shfl(sz2, 32, 64); csz2[3] = __shfl(sz2, 33, 64);

    if (l == 0) {
        const float bsc0 = bias_scales[0], bsc1 = bias_scales[1];
        // reconstruct root J (6x6) from reduced form
        float J6[6][6];
        J6[0][0] = M.j00; J6[0][1] = J6[1][0] = M.j01; J6[1][1] = M.j11;
        J6[0][2] = J6[0][3] = J6[2][0] = J6[3][0] = M.ja;
        J6[0][4] = J6[0][5] = J6[4][0] = J6[5][0] = M.jb;
        J6[1][2] = J6[1][3] = J6[2][1] = J6[3][1] = M.jc;
        J6[1][4] = J6[1][5] = J6[4][1] = J6[5][1] = M.jd;
        J6[2][2] = J6[3][3] = M.p4d; J6[2][3] = J6[3][2] = M.p4o;
        J6[2][4] = J6[2][5] = J6[3][4] = J6[3][5] = M.p4x;
        J6[4][2] = J6[5][2] = J6[4][3] = J6[5][3] = M.p4x;
        J6[4][4] = J6[5][5] = M.p4e; J6[4][5] = J6[5][4] = M.p4f;
        const float s[6] = {1.f, 1.f, sqrtf(bsc0), sqrtf(bsc1), sqrtf(bsc0), sqrtf(bsc1)};
        float Mm[6][6];
#pragma unroll
        for (int i = 0; i < 6; ++i)
#pragma unroll
            for (int j = 0; j < 6; ++j)
                Mm[i][j] = ((i == j) ? 1.f : 0.f) + s[i] * s[j] * J6[i][j];
        float Lo[6][6];
#pragma unroll
        for (int i = 0; i < 6; ++i) {
#pragma unroll
            for (int j = 0; j <= i; ++j) {
                float sum = Mm[i][j];
#pragma unroll
                for (int m = 0; m < 6; ++m) if (m < j) sum -= Lo[i][m] * Lo[j][m];
                if (i == j) Lo[i][i] = sqrtf(sum);
                else Lo[i][j] = sum / Lo[j][j];
            }
        }
        float ldet = 0.f;
#pragma unroll
        for (int i = 0; i < 6; ++i) ldet += logf(Lo[i][i]);
        ldet *= 2.f;
        const float hr[6] = {e.h0, e.h1, e.h2, e.h3, e.h4, e.h5};
        float yv[6];
#pragma unroll
        for (int i = 0; i < 6; ++i) {
            float sum = s[i] * hr[i];
#pragma unroll
            for (int m = 0; m < 6; ++m) if (m < i) sum -= Lo[i][m] * yv[m];
            yv[i] = sum / Lo[i][i];
        }
        float qd = 0.f;
#pragma unroll
        for (int i = 0; i < 6; ++i) qd += yv[i] * yv[i];
        double llc = (double)e.g - 0.5 * (double)ldet + 0.5 * (double)qd;

        // contrast coordinates: 15 per group, closed form (verified rounds 1-3)
        const float bgv[4] = {bsc0, bsc1, bsc0, bsc1};
        const double r = (double)rr;
        const double T_ = 4096.0;
#pragma unroll
        for (int gg = 0; gg < 4; ++gg) {
            const double bb = (double)bgv[gg];
            const double sumz = (double)csz[gg];
            const double sumz2 = (double)csz2[gg];
            const double Zp = sumz2 - sumz * sumz / 16.0;
            const double Sqp = (double)axv[gg] - (double)axv[4 + gg];
            llc += -0.5 * Sqp / r
                   + 0.5 * (bb / (r * (r + T_ * bb))) * Zp
                   - 7.5 * ((T_ - 1.0) * log(r) + log(r + T_ * bb))
                   - 7.5 * T_ * LOG2PI;
        }
        out[0] = (float)llc;
    }
}

extern "C" void kernel_launch(void* const* d_in, const int* in_sizes, int n_in,
                              void* d_out, int out_size, void* d_ws, size_t ws_size,
                              hipStream_t stream) {
    const float* track            = (const float*)d_in[0];
    const float* bias_scales      = (const float*)d_in[1];
    const float* obs_noise        = (const float*)d_in[2];
    const float* trans_noise      = (const float*)d_in[3];
    const float* transition_param = (const float*)d_in[4];
    float* ws = (float*)d_ws;
    int* counter = (int*)((char*)d_ws + 24576);
    float* out = (float*)d_out;

    hipMemsetAsync(counter, 0, 4, stream);   // ws is poisoned 0xAA each call
    fused_kernel<<<64, 256, 0, stream>>>(track, ws, counter, bias_scales,
                                         obs_noise, trans_noise, transition_param, out);
}